// Round 2
// baseline (1434.064 us; speedup 1.0000x reference)
//
#include <hip/hip_runtime.h>
#include <hip/hip_bf16.h>

#define Bb 64
#define Ss 20
#define Hh 128
#define Vv 50257
#define Ee 300
#define Vpad 50304   // 393*128

typedef short bf16x8 __attribute__((ext_vector_type(8)));
typedef float f32x4 __attribute__((ext_vector_type(4)));

__device__ __forceinline__ unsigned short f2bf(float f){
  unsigned u = __float_as_uint(f);
  u += 0x7fff + ((u >> 16) & 1);      // round-to-nearest-even
  return (unsigned short)(u >> 16);
}
__device__ __forceinline__ float sigm(float x){ return 1.f / (1.f + __expf(-x)); }
__device__ __forceinline__ float tanh_fast(float x){
  float e = __expf(2.f * x);
  return 1.f - 2.f / (e + 1.f);
}

// dot of contiguous weight row (global, fp32) with contiguous vector (LDS), K = 4*K4
template<int K4>
__device__ __forceinline__ float dotT(const float* __restrict__ w, const float* v){
  float a0 = 0.f, a1 = 0.f, a2 = 0.f, a3 = 0.f;
  const float4* w4 = (const float4*)w;
  const float4* v4 = (const float4*)v;
#pragma unroll
  for (int i = 0; i < K4; i++){
    float4 wv = w4[i]; float4 xv = v4[i];
    a0 = fmaf(wv.x, xv.x, a0); a1 = fmaf(wv.y, xv.y, a1);
    a2 = fmaf(wv.z, xv.z, a2); a3 = fmaf(wv.w, xv.w, a3);
  }
  return (a0 + a1) + (a2 + a3);
}

// ---------------- weight transposes (run every launch; ws is re-poisoned) ----------------

struct TMat { const float* src; float* dst; int r0, R, C; };
struct TList { TMat m[15]; };

__global__ __launch_bounds__(256) void wtrans_kernel(TList L){
  TMat t = L.m[blockIdx.y];
  int idx = blockIdx.x * 256 + threadIdx.x;
  int total = t.R * t.C;
  if (idx >= total) return;
  int o = idx / t.R;          // src col = dst row
  int i = idx - o * t.R;      // row within slice
  t.dst[idx] = t.src[(size_t)(t.r0 + i) * t.C + o];   // dst[o][i], coalesced write
}

// W_proj fp32 [128][V] -> bf16 transposed [Vpad][128] (zero-padded rows)
__global__ __launch_bounds__(256) void wpt_kernel(const float* __restrict__ Wp,
                                                  unsigned short* __restrict__ Wpt){
  __shared__ unsigned short tile[64][136];   // row stride 272B = 17*16: b128-aligned reads
  int n0 = blockIdx.x * 64;
  int tid = threadIdx.x;
  for (int idx = tid; idx < 8192; idx += 256){
    int k = idx >> 6, nn = idx & 63;
    int n = n0 + nn;
    float f = (n < Vv) ? Wp[(size_t)k * Vv + n] : 0.f;
    tile[nn][k] = f2bf(f);
  }
  __syncthreads();
  for (int idx = tid; idx < 1024; idx += 256){
    int nn = idx >> 4, c = idx & 15;
    uint4 v = *reinterpret_cast<const uint4*>(&tile[nn][c * 8]);
    *reinterpret_cast<uint4*>(Wpt + (((size_t)(n0 + nn)) << 7) + c * 8) = v;
  }
}

// ---------------- x-part precompute: emb @ W(x-rows) + bias, for all 1280 tokens ----------------

__global__ __launch_bounds__(256) void pre_kernel(
    const int* __restrict__ x, const int* __restrict__ y, const float* __restrict__ emb,
    const float* __restrict__ egx, const float* __restrict__ ecx,
    const float* __restrict__ egb, const float* __restrict__ ecb,
    const float* __restrict__ dgx, const float* __restrict__ dcx,
    const float* __restrict__ dgb, const float* __restrict__ dcb,
    float* __restrict__ epg, float* __restrict__ epc,
    float* __restrict__ dpg, float* __restrict__ dpc)
{
  __shared__ __align__(16) float er[Ee];
  int tid = threadIdx.x, ti = blockIdx.x, which = blockIdx.y;
  int tok = which ? y[ti] : x[ti];
  if (tid < 75)
    ((float4*)er)[tid] = ((const float4*)(emb + (size_t)tok * Ee))[tid];
  __syncthreads();
  const float* gx = which ? dgx : egx;
  const float* cx = which ? dcx : ecx;
  float accg = (which ? dgb : egb)[tid] + dotT<75>(gx + (size_t)tid * Ee, er);
  (which ? dpg : epg)[ti * 256 + tid] = accg;
  if (tid < 128){
    float accc = (which ? dcb : ecb)[tid] + dotT<75>(cx + (size_t)tid * Ee, er);
    (which ? dpc : epc)[ti * 128 + tid] = accc;
  }
}

// ---------------- recurrence: one block (512 thr) per batch, transposed fp32 weights ----------------
// Split-K: gates (256 outs) 2 threads each, candidates/q/attn (128 outs) 4 threads each.

__global__ __launch_bounds__(512, 1) void recur2(
    const int* __restrict__ xlen,
    const float* __restrict__ epg, const float* __restrict__ epc,
    const float* __restrict__ dpg, const float* __restrict__ dpc,
    const float* __restrict__ e0_gh_t, const float* __restrict__ e0_ch_t,
    const float* __restrict__ e1_g_t, const float* __restrict__ e1_c_t,
    const float* __restrict__ e1_gb,  const float* __restrict__ e1_cb,
    const float* __restrict__ d0_gah_t, const float* __restrict__ d0_cah_t,
    const float* __restrict__ d1_g_t, const float* __restrict__ d1_c_t,
    const float* __restrict__ d1_gb,  const float* __restrict__ d1_cb,
    const float* __restrict__ W_mem_t, const float* __restrict__ W_q_t,
    const float* __restrict__ W_attn_t, const float* __restrict__ v_att,
    unsigned short* __restrict__ na_bf)
{
  __shared__ __align__(16) float mem_s[Ss][Hh];
  __shared__ __align__(16) float keys_s[Ss][132];   // +4 pad: breaks 32-bank aliasing
  __shared__ __align__(16) float h0[Hh], h1[Hh], attn[Hh], n0[Hh], n1[Hh], rh[Hh], q[Hh], ctx[Hh];
  __shared__ __align__(16) float gates[2*Hh];
  __shared__ __align__(16) float vatt_s[Hh];
  __shared__ float part[Ss][8];

  const int tid = threadIdx.x, b = blockIdx.x;
  if (tid < Hh){ h0[tid] = 0.f; h1[tid] = 0.f; attn[tid] = 0.f; vatt_s[tid] = v_att[tid]; }
  __syncthreads();
  const int xl = xlen[b];

  const int o2 = tid >> 1, hf = tid & 1;   // pair decomposition (gates)
  const int o4 = tid >> 2, qu = tid & 3;   // quad decomposition (candidates)

  // ================= encoder =================
  for (int t = 0; t < Ss; t++){
    const int tix = b * Ss + t;
    {   // layer0 gate: 256 outs, dot len 128 -> 64 per thread
      float a = dotT<16>(e0_gh_t + o2 * 128 + hf * 64, h0 + hf * 64);
      a += __shfl_xor(a, 1);
      if (!hf){
        float sg = sigm(epg[(tix << 8) + o2] + a);
        if (o2 < Hh) rh[o2] = sg * h0[o2];   // r-half fused, no extra barrier
        else         gates[o2] = sg;         // u-half
      }
    }
    __syncthreads();
    {   // layer0 candidate: 128 outs, dot len 128 -> 32 per thread
      float a = dotT<8>(e0_ch_t + o4 * 128 + qu * 32, rh + qu * 32);
      a += __shfl_xor(a, 1); a += __shfl_xor(a, 2);
      if (!qu){
        float c = tanh_fast(epc[(tix << 7) + o4] + a);
        float u = gates[128 + o4];
        n0[o4] = u * h0[o4] + (1.f - u) * c;
      }
    }
    __syncthreads();
    {   // layer1 gate: 256 outs, dot len 256 -> 128 per thread
      const float* base = e1_g_t + o2 * 256 + hf * 128;
      float a = hf ? dotT<32>(base, h1) : dotT<32>(base, n0);
      a += __shfl_xor(a, 1);
      if (!hf){
        float sg = sigm(e1_gb[o2] + a);
        if (o2 < Hh) rh[o2] = sg * h1[o2];
        else         gates[o2] = sg;
      }
    }
    __syncthreads();
    {   // layer1 candidate + state update: 128 outs, dot len 256 -> 64 per thread
      const float* v = (qu < 2) ? n0 : rh;
      float a = dotT<16>(e1_c_t + o4 * 256 + qu * 64, v + (qu & 1) * 64);
      a += __shfl_xor(a, 1); a += __shfl_xor(a, 2);
      if (!qu){
        float c = tanh_fast(e1_cb[o4] + a);
        float u = gates[128 + o4];
        float nh = u * h1[o4] + (1.f - u) * c;
        bool vv = (t < xl);
        mem_s[t][o4] = vv ? nh : 0.f;
        h1[o4] = vv ? nh : h1[o4];
        h0[o4] = vv ? n0[o4] : h0[o4];
      }
    }
    __syncthreads();
  }

  // keys = memory @ W_mem
  for (int idx = tid; idx < Ss * Hh; idx += 512){
    int s = idx >> 7, j = idx & 127;
    keys_s[s][j] = dotT<32>(W_mem_t + j * 128, mem_s[s]);
  }
  __syncthreads();

  // ================= decoder =================
  for (int t = 0; t < Ss; t++){
    const int tix = b * Ss + t;
    {   // layer0 gate: input [attn, h0]
      const float* base = d0_gah_t + o2 * 256 + hf * 128;
      float a = hf ? dotT<32>(base, h0) : dotT<32>(base, attn);
      a += __shfl_xor(a, 1);
      if (!hf){
        float sg = sigm(dpg[(tix << 8) + o2] + a);
        if (o2 < Hh) rh[o2] = sg * h0[o2];
        else         gates[o2] = sg;
      }
    }
    __syncthreads();
    {   // layer0 candidate: input [attn, rh]
      const float* v = (qu < 2) ? attn : rh;
      float a = dotT<16>(d0_cah_t + o4 * 256 + qu * 64, v + (qu & 1) * 64);
      a += __shfl_xor(a, 1); a += __shfl_xor(a, 2);
      if (!qu){
        float c = tanh_fast(dpc[(tix << 7) + o4] + a);
        float u = gates[128 + o4];
        float nv = u * h0[o4] + (1.f - u) * c;
        n0[o4] = nv; h0[o4] = nv;            // decoder carry unconditional
      }
    }
    __syncthreads();
    {   // layer1 gate: input [n0, h1]
      const float* base = d1_g_t + o2 * 256 + hf * 128;
      float a = hf ? dotT<32>(base, h1) : dotT<32>(base, n0);
      a += __shfl_xor(a, 1);
      if (!hf){
        float sg = sigm(d1_gb[o2] + a);
        if (o2 < Hh) rh[o2] = sg * h1[o2];
        else         gates[o2] = sg;
      }
    }
    __syncthreads();
    {   // layer1 candidate: input [n0, rh]
      const float* v = (qu < 2) ? n0 : rh;
      float a = dotT<16>(d1_c_t + o4 * 256 + qu * 64, v + (qu & 1) * 64);
      a += __shfl_xor(a, 1); a += __shfl_xor(a, 2);
      if (!qu){
        float c = tanh_fast(d1_cb[o4] + a);
        float u = gates[128 + o4];
        float nh = u * h1[o4] + (1.f - u) * c;
        n1[o4] = nh; h1[o4] = nh;
      }
    }
    __syncthreads();
    {   // q = n1 @ W_q: 128 outs, dot 128 -> 32 per thread
      float a = dotT<8>(W_q_t + o4 * 128 + qu * 32, n1 + qu * 32);
      a += __shfl_xor(a, 1); a += __shfl_xor(a, 2);
      if (!qu) q[o4] = a;
    }
    __syncthreads();
    if (tid < Ss * 8){   // scores partials
      int s = tid >> 3, p = tid & 7;
      float a = 0.f;
#pragma unroll
      for (int c2 = 0; c2 < 16; c2++){
        int u2 = p * 16 + c2;
        a += tanh_fast(keys_s[s][u2] + q[u2]) * vatt_s[u2];
      }
      part[s][p] = a;
    }
    __syncthreads();
    if (tid < Hh){       // fused softmax + context (each thread redoes the tiny softmax)
      float e_[Ss];
      float mx = -3.4e38f;
#pragma unroll
      for (int s = 0; s < Ss; s++){
        float v = ((part[s][0] + part[s][1]) + (part[s][2] + part[s][3]))
                + ((part[s][4] + part[s][5]) + (part[s][6] + part[s][7]));
        v = (s < xl) ? v : -3.4e38f;
        e_[s] = v; mx = fmaxf(mx, v);
      }
      float sm = 0.f;
#pragma unroll
      for (int s = 0; s < Ss; s++){
        float e = (s < xl) ? __expf(e_[s] - mx) : 0.f;
        e_[s] = e; sm += e;
      }
      float inv = 1.f / sm;
      float a = 0.f;
#pragma unroll
      for (int s = 0; s < Ss; s++) a = fmaf(e_[s], mem_s[s][tid], a);
      ctx[tid] = a * inv;
    }
    __syncthreads();
    {   // na = [n1, ctx] @ W_attn -> next attn + projection input
      const float* v = (qu < 2) ? n1 : ctx;
      float a = dotT<16>(W_attn_t + o4 * 256 + qu * 64, v + (qu & 1) * 64);
      a += __shfl_xor(a, 1); a += __shfl_xor(a, 2);
      if (!qu){
        attn[o4] = a;
        na_bf[(tix << 7) + o4] = f2bf(a);
      }
    }
    __syncthreads();
  }
}

// ---------------- projection: MFMA, fragments straight from global (L2/L3-resident) ----------------

__global__ __launch_bounds__(256) void proj2(
    const unsigned short* __restrict__ na_bf, const unsigned short* __restrict__ Wpt,
    const float* __restrict__ b_proj, const int* __restrict__ ylen,
    float* __restrict__ out)
{
  __shared__ int yl_s[Bb];
  const int tid = threadIdx.x;
  if (tid < Bb) yl_s[tid] = ylen[tid];
  const int n0 = blockIdx.x * 128, m0 = blockIdx.y * 64;
  const int lane = tid & 63, w = tid >> 6, lm = lane & 15, qq = lane >> 4;

  f32x4 acc[4][2];
#pragma unroll
  for (int mt = 0; mt < 4; mt++){ acc[mt][0] = (f32x4){0,0,0,0}; acc[mt][1] = (f32x4){0,0,0,0}; }

#pragma unroll
  for (int ks = 0; ks < 4; ks++){
    int ko = ks * 32 + qq * 8;
    bf16x8 b0 = *(const bf16x8*)(Wpt + (((size_t)(n0 + w*32 + lm)) << 7) + ko);
    bf16x8 b1 = *(const bf16x8*)(Wpt + (((size_t)(n0 + w*32 + 16 + lm)) << 7) + ko);
#pragma unroll
    for (int mt = 0; mt < 4; mt++){
      bf16x8 a = *(const bf16x8*)(na_bf + (((size_t)(m0 + mt*16 + lm)) << 7) + ko);
      acc[mt][0] = __builtin_amdgcn_mfma_f32_16x16x32_bf16(a, b0, acc[mt][0], 0, 0, 0);
      acc[mt][1] = __builtin_amdgcn_mfma_f32_16x16x32_bf16(a, b1, acc[mt][1], 0, 0, 0);
    }
  }
  __syncthreads();   // yl_s visibility

  // C/D layout: col = lane&15, row = (lane>>4)*4 + reg
#pragma unroll
  for (int mt = 0; mt < 4; mt++){
    int row = m0 + mt*16 + qq*4;
#pragma unroll
    for (int n2 = 0; n2 < 2; n2++){
      int col = n0 + w*32 + n2*16 + lm;
      if (col < Vv){
        float bp = b_proj[col];
#pragma unroll
        for (int r = 0; r < 4; r++){
          int rr = row + r;
          int bb = rr / Ss;
          int tt = rr - bb * Ss;
          float val = (tt < yl_s[bb]) ? (acc[mt][n2][r] + bp) : 0.f;
          out[(size_t)rr * Vv + col] = val;
        }
      }
    }
  }
}

extern "C" void kernel_launch(void* const* d_in, const int* in_sizes, int n_in,
                              void* d_out, int out_size, void* d_ws, size_t ws_size,
                              hipStream_t stream) {
  const int*   x        = (const int*)d_in[0];
  const int*   x_length = (const int*)d_in[1];
  const int*   y        = (const int*)d_in[2];
  const int*   y_length = (const int*)d_in[3];
  const float* emb      = (const float*)d_in[4];
  const float* e0_gk = (const float*)d_in[5];  const float* e0_gb = (const float*)d_in[6];
  const float* e0_ck = (const float*)d_in[7];  const float* e0_cb = (const float*)d_in[8];
  const float* e1_gk = (const float*)d_in[9];  const float* e1_gb = (const float*)d_in[10];
  const float* e1_ck = (const float*)d_in[11]; const float* e1_cb = (const float*)d_in[12];
  const float* d0_gk = (const float*)d_in[13]; const float* d0_gb = (const float*)d_in[14];
  const float* d0_ck = (const float*)d_in[15]; const float* d0_cb = (const float*)d_in[16];
  const float* d1_gk = (const float*)d_in[17]; const float* d1_gb = (const float*)d_in[18];
  const float* d1_ck = (const float*)d_in[19]; const float* d1_cb = (const float*)d_in[20];
  const float* W_mem = (const float*)d_in[21]; const float* W_q   = (const float*)d_in[22];
  const float* v_att = (const float*)d_in[23]; const float* W_attn= (const float*)d_in[24];
  const float* W_proj= (const float*)d_in[25]; const float* b_proj= (const float*)d_in[26];
  float* out = (float*)d_out;

  // ---- workspace carve-up (256B-aligned segments) ----
  size_t off = 0;
  auto alloc = [&](size_t bytes) -> void* {
    void* p = (char*)d_ws + off;
    off += (bytes + 255) & ~(size_t)255;
    return p;
  };
  unsigned short* Wpt   = (unsigned short*)alloc((size_t)Vpad * 128 * 2);
  unsigned short* na_bf = (unsigned short*)alloc((size_t)Bb * Ss * Hh * 2);
  float* epg = (float*)alloc((size_t)Bb*Ss*256*4);
  float* epc = (float*)alloc((size_t)Bb*Ss*128*4);
  float* dpg = (float*)alloc((size_t)Bb*Ss*256*4);
  float* dpc = (float*)alloc((size_t)Bb*Ss*128*4);
  float* e0_gx_t  = (float*)alloc(256*300*4);
  float* e0_gh_t  = (float*)alloc(256*128*4);
  float* e0_cx_t  = (float*)alloc(128*300*4);
  float* e0_ch_t  = (float*)alloc(128*128*4);
  float* e1_g_t   = (float*)alloc(256*256*4);
  float* e1_c_t   = (float*)alloc(128*256*4);
  float* d0_gx_t  = (float*)alloc(256*300*4);
  float* d0_gah_t = (float*)alloc(256*256*4);
  float* d0_cx_t  = (float*)alloc(128*300*4);
  float* d0_cah_t = (float*)alloc(128*256*4);
  float* d1_g_t   = (float*)alloc(256*256*4);
  float* d1_c_t   = (float*)alloc(128*256*4);
  float* W_mem_t  = (float*)alloc(128*128*4);
  float* W_q_t    = (float*)alloc(128*128*4);
  float* W_attn_t = (float*)alloc(128*256*4);

  TList L;
  L.m[0]  = { e0_gk, e0_gx_t,    0, 300, 256 };
  L.m[1]  = { e0_gk, e0_gh_t,  300, 128, 256 };
  L.m[2]  = { e0_ck, e0_cx_t,    0, 300, 128 };
  L.m[3]  = { e0_ck, e0_ch_t,  300, 128, 128 };
  L.m[4]  = { e1_gk, e1_g_t,     0, 256, 256 };
  L.m[5]  = { e1_ck, e1_c_t,     0, 256, 128 };
  L.m[6]  = { d0_gk, d0_gx_t,    0, 300, 256 };
  L.m[7]  = { d0_gk, d0_gah_t, 300, 256, 256 };
  L.m[8]  = { d0_ck, d0_cx_t,    0, 300, 128 };
  L.m[9]  = { d0_ck, d0_cah_t, 300, 256, 128 };
  L.m[10] = { d1_gk, d1_g_t,     0, 256, 256 };
  L.m[11] = { d1_ck, d1_c_t,     0, 256, 128 };
  L.m[12] = { W_mem, W_mem_t,    0, 128, 128 };
  L.m[13] = { W_q,   W_q_t,      0, 128, 128 };
  L.m[14] = { W_attn,W_attn_t,   0, 256, 128 };

  wtrans_kernel<<<dim3(300, 15), 256, 0, stream>>>(L);
  wpt_kernel<<<Vpad / 64, 256, 0, stream>>>(W_proj, Wpt);
  pre_kernel<<<dim3(Bb * Ss, 2), 256, 0, stream>>>(
      x, y, emb, e0_gx_t, e0_cx_t, e0_gb, e0_cb,
      d0_gx_t, d0_cx_t, d0_gb, d0_cb, epg, epc, dpg, dpc);
  recur2<<<Bb, 512, 0, stream>>>(
      x_length, epg, epc, dpg, dpc,
      e0_gh_t, e0_ch_t, e1_g_t, e1_c_t, e1_gb, e1_cb,
      d0_gah_t, d0_cah_t, d1_g_t, d1_c_t, d1_gb, d1_cb,
      W_mem_t, W_q_t, W_attn_t, v_att, na_bf);
  proj2<<<dim3(Vpad / 128, (Bb * Ss) / 64), 256, 0, stream>>>(
      na_bf, Wpt, b_proj, y_length, out);
}